// Round 3
// baseline (15531.183 us; speedup 1.0000x reference)
//
#include <hip/hip_runtime.h>
#include <hip/hip_bf16.h>

typedef __hip_bfloat16 bf16;

#define D 512
#define H 8
#define DK 64
#define NL 6
#define V 32000
#define FF 2048
#define B 8
#define S 128
#define NTOK (B * S)   // 1024

// ---------------------------------------------------------------------------
// Embedding: x[row, d] = tok_emb[ids[row], d] + pos_emb[row%128, d]
// ---------------------------------------------------------------------------
__global__ void embed_kernel(const int* __restrict__ ids,
                             const float* __restrict__ tok,
                             const float* __restrict__ pos,
                             float* __restrict__ X)
{
    int row = blockIdx.x;            // 0..1023
    int s   = row & (S - 1);
    int id  = ids[row];
    for (int d = threadIdx.x; d < D; d += 256) {
        X[row * D + d] = tok[(size_t)id * D + d] + pos[s * D + d];
    }
}

// ---------------------------------------------------------------------------
// LayerNorm: one wave (64 lanes) per row of 512
// ---------------------------------------------------------------------------
__global__ void ln_kernel(const float* __restrict__ X,
                          const float* __restrict__ g,
                          const float* __restrict__ bta,
                          float* __restrict__ Y)
{
    int row  = blockIdx.x;
    int lane = threadIdx.x;          // 64
    float v[8];
    float sum = 0.f;
#pragma unroll
    for (int i = 0; i < 8; ++i) {
        v[i] = X[row * D + i * 64 + lane];
        sum += v[i];
    }
#pragma unroll
    for (int off = 32; off > 0; off >>= 1) sum += __shfl_xor(sum, off);
    float mu = sum * (1.f / D);
    float var = 0.f;
#pragma unroll
    for (int i = 0; i < 8; ++i) { float d = v[i] - mu; var += d * d; }
#pragma unroll
    for (int off = 32; off > 0; off >>= 1) var += __shfl_xor(var, off);
    var *= (1.f / D);
    float r = rsqrtf(var + 1e-6f);
#pragma unroll
    for (int i = 0; i < 8; ++i) {
        int d = i * 64 + lane;
        Y[row * D + d] = (v[i] - mu) * r * g[d] + bta[d];
    }
}

// ---------------------------------------------------------------------------
// GEMM (NN): C[M,N] = A[M,K] @ W[K,N] + bias (+resid) (+relu)
//   all fp32.  64x64 tile, BK=16, 4x4 per thread, 256 thr.
// ---------------------------------------------------------------------------
#define BM 64
#define BN 64
#define BK 16
#define PADL 4   // LDS pad

__global__ void gemm_nn(const float* __restrict__ A,
                        const float* __restrict__ W,
                        const float* __restrict__ bias,
                        const float* resid,      // may alias C; no restrict
                        float* C,
                        int M, int N, int K, int relu)
{
    __shared__ float As[BK][BM + PADL];
    __shared__ float Ws[BK][BN + PADL];
    int tid = threadIdx.x;
    int tx = tid & 15, ty = tid >> 4;
    int row0 = blockIdx.y * BM;
    int col0 = blockIdx.x * BN;
    float c[4][4] = {};
    for (int k0 = 0; k0 < K; k0 += BK) {
        for (int i = tid; i < BM * BK; i += 256) {
            int m = i / BK, k = i % BK;
            As[k][m] = A[(size_t)(row0 + m) * K + k0 + k];
        }
        for (int i = tid; i < BK * BN; i += 256) {
            int k = i / BN, n = i % BN;
            Ws[k][n] = W[(size_t)(k0 + k) * N + col0 + n];
        }
        __syncthreads();
#pragma unroll
        for (int kk = 0; kk < BK; ++kk) {
            float a[4], b[4];
#pragma unroll
            for (int i = 0; i < 4; ++i) a[i] = As[kk][ty * 4 + i];
#pragma unroll
            for (int j = 0; j < 4; ++j) b[j] = Ws[kk][tx * 4 + j];
#pragma unroll
            for (int i = 0; i < 4; ++i)
#pragma unroll
                for (int j = 0; j < 4; ++j) c[i][j] += a[i] * b[j];
        }
        __syncthreads();
    }
#pragma unroll
    for (int i = 0; i < 4; ++i) {
        int m = row0 + ty * 4 + i;
#pragma unroll
        for (int j = 0; j < 4; ++j) {
            int n = col0 + tx * 4 + j;
            float val = c[i][j] + bias[n];
            if (resid) val += resid[(size_t)m * N + n];
            if (relu) val = fmaxf(val, 0.f);
            C[(size_t)m * N + n] = val;
        }
    }
}

// ---------------------------------------------------------------------------
// GEMM (NT) for generator: C[m,n] = sum_k A[m,k] * Bm[n,k];  C written fp32
// ---------------------------------------------------------------------------
__global__ void gemm_nt(const float* __restrict__ A,
                        const float* __restrict__ Bm,
                        float* __restrict__ Cout,
                        int M, int N, int K)
{
    __shared__ float As[BK][BM + PADL];
    __shared__ float Bs[BK][BN + PADL];
    int tid = threadIdx.x;
    int tx = tid & 15, ty = tid >> 4;
    int row0 = blockIdx.y * BM;
    int col0 = blockIdx.x * BN;
    float c[4][4] = {};
    for (int k0 = 0; k0 < K; k0 += BK) {
        for (int i = tid; i < BM * BK; i += 256) {
            int m = i / BK, k = i % BK;
            As[k][m] = A[(size_t)(row0 + m) * K + k0 + k];
        }
        for (int i = tid; i < BN * BK; i += 256) {
            int n = i / BK, k = i % BK;
            Bs[k][n] = Bm[(size_t)(col0 + n) * K + k0 + k];
        }
        __syncthreads();
#pragma unroll
        for (int kk = 0; kk < BK; ++kk) {
            float a[4], b[4];
#pragma unroll
            for (int i = 0; i < 4; ++i) a[i] = As[kk][ty * 4 + i];
#pragma unroll
            for (int j = 0; j < 4; ++j) b[j] = Bs[kk][tx * 4 + j];
#pragma unroll
            for (int i = 0; i < 4; ++i)
#pragma unroll
                for (int j = 0; j < 4; ++j) c[i][j] += a[i] * b[j];
        }
        __syncthreads();
    }
#pragma unroll
    for (int i = 0; i < 4; ++i) {
        int m = row0 + ty * 4 + i;
#pragma unroll
        for (int j = 0; j < 4; ++j) {
            int n = col0 + tx * 4 + j;
            Cout[(size_t)m * N + n] = c[i][j];
        }
    }
}

// ---------------------------------------------------------------------------
// Attention: one block per (b, h, 32-q-row chunk); K (fp32) + V (bf16) in LDS
// (51.7 KB total, under the 64 KB/WG static-LDS limit).
// Q,K,V,O layout: [b*S + t, h*DK + d].
// mask_ids: per-key token ids (PAD==1 masks); causal adds k>q mask.
// ---------------------------------------------------------------------------
__global__ void attn_kernel(const float* __restrict__ Qb,
                            const float* __restrict__ Kb,
                            const float* __restrict__ Vb,
                            float* __restrict__ Ob,
                            const int* __restrict__ mask_ids,
                            int causal)
{
    __shared__ float Ks[128][DK + 1];
    __shared__ bf16  Vs[128][DK + 2];
    __shared__ float Qs[2][DK];
    __shared__ float sc[2][128];

    int qc = blockIdx.x;   // 0..3
    int h  = blockIdx.y;
    int b  = blockIdx.z;
    int tid = threadIdx.x; // 256

    for (int i = tid; i < 128 * DK; i += 256) {
        int t = i >> 6, d = i & 63;
        Ks[t][d] = Kb[(size_t)(b * S + t) * D + h * DK + d];
        Vs[t][d] = __float2bfloat16(Vb[(size_t)(b * S + t) * D + h * DK + d]);
    }
    __syncthreads();

    int half = tid >> 7;       // 0/1
    int lane = tid & 127;      // key index / d index
    bool key_pad = (mask_ids[b * S + lane] == 1);

    for (int qi = 0; qi < 32; qi += 2) {
        int q = qc * 32 + qi + half;
        if (lane < DK)
            Qs[half][lane] = Qb[(size_t)(b * S + q) * D + h * DK + lane];
        __syncthreads();

        float s = 0.f;
#pragma unroll
        for (int d = 0; d < DK; ++d) s += Qs[half][d] * Ks[lane][d];
        s *= 0.125f;   // 1/sqrt(64)
        bool masked = key_pad || (causal && lane > q);
        sc[half][lane] = masked ? -1e30f : s;
        __syncthreads();

        float m = -1e30f;
        for (int t = 0; t < 128; ++t) m = fmaxf(m, sc[half][t]);
        float e = expf(sc[half][lane] - m);
        __syncthreads();               // all reads of sc done
        sc[half][lane] = e;
        __syncthreads();

        float sum = 0.f;
        for (int t = 0; t < 128; ++t) sum += sc[half][t];
        float inv = 1.f / sum;

        if (lane < DK) {
            float o = 0.f;
            for (int t = 0; t < 128; ++t)
                o += sc[half][t] * __bfloat162float(Vs[t][lane]);
            Ob[(size_t)(b * S + q) * D + h * DK + lane] = o * inv;
        }
        __syncthreads();
    }
}

// ---------------------------------------------------------------------------
// Per-row log-sum-exp over V=32000 fp32 logits -> c[row] = m + log(sum exp)
// ---------------------------------------------------------------------------
__global__ void lse_kernel(const float* __restrict__ logits,
                           float* __restrict__ c)
{
    __shared__ float ms[256], ls[256];
    int row = blockIdx.x;
    int tid = threadIdx.x;
    float m = -1e30f, l = 0.f;
    for (int j = tid; j < V; j += 256) {
        float x = logits[(size_t)row * V + j];
        if (x > m) { l = l * expf(m - x) + 1.f; m = x; }
        else       { l += expf(x - m); }
    }
    ms[tid] = m; ls[tid] = l;
    __syncthreads();
    for (int s2 = 128; s2 > 0; s2 >>= 1) {
        if (tid < s2) {
            float m1 = ms[tid], l1 = ls[tid];
            float m2 = ms[tid + s2], l2 = ls[tid + s2];
            float M = fmaxf(m1, m2);
            ls[tid] = l1 * expf(m1 - M) + l2 * expf(m2 - M);
            ms[tid] = M;
        }
        __syncthreads();
    }
    if (tid == 0) c[row] = ms[0] + logf(ls[0]);
}

__global__ void lsub_kernel(float* __restrict__ out, const float* __restrict__ c)
{
    int row = blockIdx.y;
    int j = blockIdx.x * 256 + threadIdx.x;  // grid.x = 125
    size_t idx = (size_t)row * V + j;
    out[idx] = out[idx] - c[row];
}

// ---------------------------------------------------------------------------
// Host orchestration
// ---------------------------------------------------------------------------
extern "C" void kernel_launch(void* const* d_in, const int* in_sizes, int n_in,
                              void* d_out, int out_size, void* d_ws, size_t ws_size,
                              hipStream_t stream)
{
    const int*   src        = (const int*)d_in[0];
    const int*   tgt        = (const int*)d_in[1];
    const float* tok_emb    = (const float*)d_in[2];
    const float* pos_emb    = (const float*)d_in[3];
    const float* enc_attn_w = (const float*)d_in[4];
    const float* enc_attn_b = (const float*)d_in[5];
    const float* enc_ffn_w1 = (const float*)d_in[6];
    const float* enc_ffn_b1 = (const float*)d_in[7];
    const float* enc_ffn_w2 = (const float*)d_in[8];
    const float* enc_ffn_b2 = (const float*)d_in[9];
    const float* enc_ln     = (const float*)d_in[10];
    const float* enc_fln    = (const float*)d_in[11];
    const float* dec_attn_w = (const float*)d_in[12];
    const float* dec_attn_b = (const float*)d_in[13];
    const float* dec_ffn_w1 = (const float*)d_in[14];
    const float* dec_ffn_b1 = (const float*)d_in[15];
    const float* dec_ffn_w2 = (const float*)d_in[16];
    const float* dec_ffn_b2 = (const float*)d_in[17];
    const float* dec_ln     = (const float*)d_in[18];
    const float* dec_fln    = (const float*)d_in[19];
    float* out = (float*)d_out;

    float* ws  = (float*)d_ws;
    const size_t TOKD = (size_t)NTOK * D;   // 524288
    float* x   = ws;
    float* h   = x   + TOKD;   // also reused as attention output (ao)
    float* q   = h   + TOKD;
    float* k   = q   + TOKD;
    float* v   = k   + TOKD;
    float* mem = v   + TOKD;
    float* mid = mem + TOKD;                // NTOK*FF = 2097152
    float* red = mid + (size_t)NTOK * FF;   // 1024
    float* ao  = h;                          // alias: h is dead once q/k/v exist

    dim3 blk256(256), blk64(64);
    dim3 gD(D / BN, NTOK / BM);       // GEMM -> N=512
    dim3 gFF(FF / BN, NTOK / BM);     // GEMM -> N=2048
    dim3 gAttn(4, H, B);
    dim3 gGen(V / BN, NTOK / BM);     // 500 x 16

    // ================= encoder =================
    embed_kernel<<<NTOK, blk256, 0, stream>>>(src, tok_emb, pos_emb, x);
    for (int i = 0; i < NL; ++i) {
        const float* w  = enc_attn_w + (size_t)i * 4 * D * D;
        const float* bb = enc_attn_b + (size_t)i * 4 * D;
        const float* ln0 = enc_ln + (size_t)((i * 2 + 0) * 2) * D;
        const float* ln1 = enc_ln + (size_t)((i * 2 + 1) * 2) * D;

        ln_kernel<<<NTOK, blk64, 0, stream>>>(x, ln0, ln0 + D, h);
        gemm_nn<<<gD, blk256, 0, stream>>>(h, w + 0 * (size_t)D * D, bb + 0 * D, nullptr, q, NTOK, D, D, 0);
        gemm_nn<<<gD, blk256, 0, stream>>>(h, w + 1 * (size_t)D * D, bb + 1 * D, nullptr, k, NTOK, D, D, 0);
        gemm_nn<<<gD, blk256, 0, stream>>>(h, w + 2 * (size_t)D * D, bb + 2 * D, nullptr, v, NTOK, D, D, 0);
        attn_kernel<<<gAttn, blk256, 0, stream>>>(q, k, v, ao, src, 0);
        gemm_nn<<<gD, blk256, 0, stream>>>(ao, w + 3 * (size_t)D * D, bb + 3 * D, x, x, NTOK, D, D, 0);

        ln_kernel<<<NTOK, blk64, 0, stream>>>(x, ln1, ln1 + D, h);
        gemm_nn<<<gFF, blk256, 0, stream>>>(h, enc_ffn_w1 + (size_t)i * D * FF, enc_ffn_b1 + (size_t)i * FF, nullptr, mid, NTOK, FF, D, 1);
        gemm_nn<<<gD, blk256, 0, stream>>>(mid, enc_ffn_w2 + (size_t)i * FF * D, enc_ffn_b2 + (size_t)i * D, x, x, NTOK, D, FF, 0);
    }
    ln_kernel<<<NTOK, blk64, 0, stream>>>(x, enc_fln, enc_fln + D, mem);

    // ================= decoder =================
    embed_kernel<<<NTOK, blk256, 0, stream>>>(tgt, tok_emb, pos_emb, x);
    for (int i = 0; i < NL; ++i) {
        const float* w  = dec_attn_w + (size_t)i * 8 * D * D;
        const float* bb = dec_attn_b + (size_t)i * 8 * D;
        const float* ln0 = dec_ln + (size_t)((i * 3 + 0) * 2) * D;
        const float* ln1 = dec_ln + (size_t)((i * 3 + 1) * 2) * D;
        const float* ln2 = dec_ln + (size_t)((i * 3 + 2) * 2) * D;

        // self-attention (causal)
        ln_kernel<<<NTOK, blk64, 0, stream>>>(x, ln0, ln0 + D, h);
        gemm_nn<<<gD, blk256, 0, stream>>>(h, w + 0 * (size_t)D * D, bb + 0 * D, nullptr, q, NTOK, D, D, 0);
        gemm_nn<<<gD, blk256, 0, stream>>>(h, w + 1 * (size_t)D * D, bb + 1 * D, nullptr, k, NTOK, D, D, 0);
        gemm_nn<<<gD, blk256, 0, stream>>>(h, w + 2 * (size_t)D * D, bb + 2 * D, nullptr, v, NTOK, D, D, 0);
        attn_kernel<<<gAttn, blk256, 0, stream>>>(q, k, v, ao, tgt, 1);
        gemm_nn<<<gD, blk256, 0, stream>>>(ao, w + 3 * (size_t)D * D, bb + 3 * D, x, x, NTOK, D, D, 0);

        // cross-attention (keys/values from encoder mem)
        ln_kernel<<<NTOK, blk64, 0, stream>>>(x, ln1, ln1 + D, h);
        gemm_nn<<<gD, blk256, 0, stream>>>(h,   w + 4 * (size_t)D * D, bb + 4 * D, nullptr, q, NTOK, D, D, 0);
        gemm_nn<<<gD, blk256, 0, stream>>>(mem, w + 5 * (size_t)D * D, bb + 5 * D, nullptr, k, NTOK, D, D, 0);
        gemm_nn<<<gD, blk256, 0, stream>>>(mem, w + 6 * (size_t)D * D, bb + 6 * D, nullptr, v, NTOK, D, D, 0);
        attn_kernel<<<gAttn, blk256, 0, stream>>>(q, k, v, ao, src, 0);
        gemm_nn<<<gD, blk256, 0, stream>>>(ao, w + 7 * (size_t)D * D, bb + 7 * D, x, x, NTOK, D, D, 0);

        // FFN
        ln_kernel<<<NTOK, blk64, 0, stream>>>(x, ln2, ln2 + D, h);
        gemm_nn<<<gFF, blk256, 0, stream>>>(h, dec_ffn_w1 + (size_t)i * D * FF, dec_ffn_b1 + (size_t)i * FF, nullptr, mid, NTOK, FF, D, 1);
        gemm_nn<<<gD, blk256, 0, stream>>>(mid, dec_ffn_w2 + (size_t)i * FF * D, dec_ffn_b2 + (size_t)i * D, x, x, NTOK, D, FF, 0);
    }
    ln_kernel<<<NTOK, blk64, 0, stream>>>(x, dec_fln, dec_fln + D, h);

    // ================= generator =================
    gemm_nt<<<gGen, blk256, 0, stream>>>(h, tok_emb, out, NTOK, V, D);
    lse_kernel<<<NTOK, blk256, 0, stream>>>(out, red);
    lsub_kernel<<<dim3(V / 256, NTOK), blk256, 0, stream>>>(out, red);
}

// Round 4
// 12662.857 us; speedup vs baseline: 1.2265x; 1.2265x over previous
//
#include <hip/hip_runtime.h>
#include <hip/hip_bf16.h>

typedef __hip_bfloat16 bf16;
typedef __attribute__((ext_vector_type(8))) short bf8_t;  // 8 bf16 (4 VGPRs)
typedef __attribute__((ext_vector_type(4))) float f4_t;   // 4 fp32 acc

#define D 512
#define H 8
#define DK 64
#define NL 6
#define V 32000
#define FF 2048
#define B 8
#define S 128
#define NTOK (B * S)   // 1024

static __device__ inline short f2bs(float x) {
    __hip_bfloat16 h = __float2bfloat16(x);
    return *reinterpret_cast<short*>(&h);
}

// ---------------------------------------------------------------------------
// Embedding
// ---------------------------------------------------------------------------
__global__ void embed_kernel(const int* __restrict__ ids,
                             const float* __restrict__ tok,
                             const float* __restrict__ pos,
                             float* __restrict__ X)
{
    int row = blockIdx.x;
    int s   = row & (S - 1);
    int id  = ids[row];
    for (int d = threadIdx.x; d < D; d += 256) {
        X[row * D + d] = tok[(size_t)id * D + d] + pos[s * D + d];
    }
}

// ---------------------------------------------------------------------------
// LayerNorm: one wave per row of 512
// ---------------------------------------------------------------------------
__global__ void ln_kernel(const float* __restrict__ X,
                          const float* __restrict__ g,
                          const float* __restrict__ bta,
                          float* __restrict__ Y)
{
    int row  = blockIdx.x;
    int lane = threadIdx.x;          // 64
    float v[8];
    float sum = 0.f;
#pragma unroll
    for (int i = 0; i < 8; ++i) {
        v[i] = X[row * D + i * 64 + lane];
        sum += v[i];
    }
#pragma unroll
    for (int off = 32; off > 0; off >>= 1) sum += __shfl_xor(sum, off);
    float mu = sum * (1.f / D);
    float var = 0.f;
#pragma unroll
    for (int i = 0; i < 8; ++i) { float d = v[i] - mu; var += d * d; }
#pragma unroll
    for (int off = 32; off > 0; off >>= 1) var += __shfl_xor(var, off);
    var *= (1.f / D);
    float r = rsqrtf(var + 1e-6f);
#pragma unroll
    for (int i = 0; i < 8; ++i) {
        int d = i * 64 + lane;
        Y[row * D + d] = (v[i] - mu) * r * g[d] + bta[d];
    }
}

// ---------------------------------------------------------------------------
// MFMA GEMM (NN): C[z] = A @ (W + z*wzs) + bias[z]  (+resid) (+relu)
//   A fp32 [M,K]; W fp32 [K,Nw]; staged to LDS as bf16; fp32 accumulate.
//   64x64 tile, BK=32, 256 thr = 4 waves; wave computes 16 rows x 64 cols
//   via 4x mfma_f32_16x16x32_bf16 per K-step.
// Fragment layouts [measured m89/m120]:
//   A-frag: lane holds A[m=lane&15][k=(lane>>4)*8 + j], j=0..7
//   B-frag: lane holds B[k=(lane>>4)*8 + j][n=lane&15]
//   C/D:    col=lane&15, row=(lane>>4)*4 + reg
// ---------------------------------------------------------------------------
__global__ __launch_bounds__(256) void mgemm(
    const float* __restrict__ A, const float* __restrict__ W,
    const float* __restrict__ bias, const float* resid, float* C,
    int M, int K, int Nw, int relu,
    long wzs, long bzs, long ozs)
{
    // row stride 40 shorts = 80 B (16B-aligned, breaks pow2 bank stride)
    __shared__ __align__(16) short As[64][40];
    __shared__ __align__(16) short Bs[64][40];

    int z = blockIdx.z;
    const float* Wz = W + (size_t)z * wzs;
    const float* bz = bias + (size_t)z * bzs;
    float*       Cz = C + (size_t)z * ozs;
    const float* Rz = resid;   // only used when gridDim.z == 1

    int tid  = threadIdx.x;
    int row0 = blockIdx.y * 64, col0 = blockIdx.x * 64;
    int wv   = tid >> 6, ln = tid & 63;
    int m16  = ln & 15, quad = ln >> 4;

    f4_t acc[4];
#pragma unroll
    for (int j = 0; j < 4; ++j) acc[j] = (f4_t){0.f, 0.f, 0.f, 0.f};

    for (int k0 = 0; k0 < K; k0 += 32) {
        // stage A tile 64x32 (global coalesced over k; bf16 convert)
        for (int i = tid; i < 2048; i += 256) {
            int m = i >> 5, k = i & 31;
            As[m][k] = f2bs(A[(size_t)(row0 + m) * K + k0 + k]);
        }
        // stage B tile 32x64, transposed to n-major (global coalesced over n)
        for (int i = tid; i < 2048; i += 256) {
            int k = i >> 6, n = i & 63;
            Bs[n][k] = f2bs(Wz[(size_t)(k0 + k) * Nw + col0 + n]);
        }
        __syncthreads();

        bf8_t a = *(const bf8_t*)&As[wv * 16 + m16][quad * 8];
#pragma unroll
        for (int j = 0; j < 4; ++j) {
            bf8_t b = *(const bf8_t*)&Bs[j * 16 + m16][quad * 8];
            acc[j] = __builtin_amdgcn_mfma_f32_16x16x32_bf16(a, b, acc[j], 0, 0, 0);
        }
        __syncthreads();
    }

#pragma unroll
    for (int j = 0; j < 4; ++j) {
        int col = col0 + j * 16 + m16;
        float bv = bz[col];
#pragma unroll
        for (int r = 0; r < 4; ++r) {
            int row = row0 + wv * 16 + quad * 4 + r;
            float val = acc[j][r] + bv;
            if (Rz) val += Rz[(size_t)row * Nw + col];
            if (relu) val = fmaxf(val, 0.f);
            Cz[(size_t)row * Nw + col] = val;
        }
    }
}

// ---------------------------------------------------------------------------
// MFMA GEMM (NT) for generator: C[m,n] = sum_k A[m,k] * Bm[n,k]; C fp32
// ---------------------------------------------------------------------------
__global__ __launch_bounds__(256) void gemm_nt_mfma(
    const float* __restrict__ A, const float* __restrict__ Bm,
    float* __restrict__ C, int M, int N, int K)
{
    __shared__ __align__(16) short As[64][40];
    __shared__ __align__(16) short Bs[64][40];

    int tid  = threadIdx.x;
    int row0 = blockIdx.y * 64, col0 = blockIdx.x * 64;
    int wv   = tid >> 6, ln = tid & 63;
    int m16  = ln & 15, quad = ln >> 4;

    f4_t acc[4];
#pragma unroll
    for (int j = 0; j < 4; ++j) acc[j] = (f4_t){0.f, 0.f, 0.f, 0.f};

    for (int k0 = 0; k0 < K; k0 += 32) {
        for (int i = tid; i < 2048; i += 256) {
            int m = i >> 5, k = i & 31;
            As[m][k] = f2bs(A[(size_t)(row0 + m) * K + k0 + k]);
        }
        for (int i = tid; i < 2048; i += 256) {
            int n = i >> 5, k = i & 31;
            Bs[n][k] = f2bs(Bm[(size_t)(col0 + n) * K + k0 + k]);
        }
        __syncthreads();

        bf8_t a = *(const bf8_t*)&As[wv * 16 + m16][quad * 8];
#pragma unroll
        for (int j = 0; j < 4; ++j) {
            bf8_t b = *(const bf8_t*)&Bs[j * 16 + m16][quad * 8];
            acc[j] = __builtin_amdgcn_mfma_f32_16x16x32_bf16(a, b, acc[j], 0, 0, 0);
        }
        __syncthreads();
    }

#pragma unroll
    for (int j = 0; j < 4; ++j) {
        int col = col0 + j * 16 + m16;
#pragma unroll
        for (int r = 0; r < 4; ++r) {
            int row = row0 + wv * 16 + quad * 4 + r;
            C[(size_t)row * N + col] = acc[j][r];
        }
    }
}

// ---------------------------------------------------------------------------
// Attention (unchanged fp32 path)
// ---------------------------------------------------------------------------
__global__ void attn_kernel(const float* __restrict__ Qb,
                            const float* __restrict__ Kb,
                            const float* __restrict__ Vb,
                            float* __restrict__ Ob,
                            const int* __restrict__ mask_ids,
                            int causal)
{
    __shared__ float Ks[128][DK + 1];
    __shared__ bf16  Vs[128][DK + 2];
    __shared__ float Qs[2][DK];
    __shared__ float sc[2][128];

    int qc = blockIdx.x;
    int h  = blockIdx.y;
    int b  = blockIdx.z;
    int tid = threadIdx.x;

    for (int i = tid; i < 128 * DK; i += 256) {
        int t = i >> 6, d = i & 63;
        Ks[t][d] = Kb[(size_t)(b * S + t) * D + h * DK + d];
        Vs[t][d] = __float2bfloat16(Vb[(size_t)(b * S + t) * D + h * DK + d]);
    }
    __syncthreads();

    int half = tid >> 7;
    int lane = tid & 127;
    bool key_pad = (mask_ids[b * S + lane] == 1);

    for (int qi = 0; qi < 32; qi += 2) {
        int q = qc * 32 + qi + half;
        if (lane < DK)
            Qs[half][lane] = Qb[(size_t)(b * S + q) * D + h * DK + lane];
        __syncthreads();

        float s = 0.f;
#pragma unroll
        for (int d = 0; d < DK; ++d) s += Qs[half][d] * Ks[lane][d];
        s *= 0.125f;
        bool masked = key_pad || (causal && lane > q);
        sc[half][lane] = masked ? -1e30f : s;
        __syncthreads();

        float m = -1e30f;
        for (int t = 0; t < 128; ++t) m = fmaxf(m, sc[half][t]);
        float e = expf(sc[half][lane] - m);
        __syncthreads();
        sc[half][lane] = e;
        __syncthreads();

        float sum = 0.f;
        for (int t = 0; t < 128; ++t) sum += sc[half][t];
        float inv = 1.f / sum;

        if (lane < DK) {
            float o = 0.f;
            for (int t = 0; t < 128; ++t)
                o += sc[half][t] * __bfloat162float(Vs[t][lane]);
            Ob[(size_t)(b * S + q) * D + h * DK + lane] = o * inv;
        }
        __syncthreads();
    }
}

// ---------------------------------------------------------------------------
// log-softmax pieces
// ---------------------------------------------------------------------------
__global__ void lse_kernel(const float* __restrict__ logits,
                           float* __restrict__ c)
{
    __shared__ float ms[256], ls[256];
    int row = blockIdx.x;
    int tid = threadIdx.x;
    float m = -1e30f, l = 0.f;
    for (int j = tid; j < V; j += 256) {
        float x = logits[(size_t)row * V + j];
        if (x > m) { l = l * expf(m - x) + 1.f; m = x; }
        else       { l += expf(x - m); }
    }
    ms[tid] = m; ls[tid] = l;
    __syncthreads();
    for (int s2 = 128; s2 > 0; s2 >>= 1) {
        if (tid < s2) {
            float m1 = ms[tid], l1 = ls[tid];
            float m2 = ms[tid + s2], l2 = ls[tid + s2];
            float M = fmaxf(m1, m2);
            ls[tid] = l1 * expf(m1 - M) + l2 * expf(m2 - M);
            ms[tid] = M;
        }
        __syncthreads();
    }
    if (tid == 0) c[row] = ms[0] + logf(ls[0]);
}

__global__ void lsub_kernel(float* __restrict__ out, const float* __restrict__ c)
{
    int row = blockIdx.y;
    int j = blockIdx.x * 256 + threadIdx.x;
    size_t idx = (size_t)row * V + j;
    out[idx] = out[idx] - c[row];
}

// ---------------------------------------------------------------------------
// Host orchestration
// ---------------------------------------------------------------------------
extern "C" void kernel_launch(void* const* d_in, const int* in_sizes, int n_in,
                              void* d_out, int out_size, void* d_ws, size_t ws_size,
                              hipStream_t stream)
{
    const int*   src        = (const int*)d_in[0];
    const int*   tgt        = (const int*)d_in[1];
    const float* tok_emb    = (const float*)d_in[2];
    const float* pos_emb    = (const float*)d_in[3];
    const float* enc_attn_w = (const float*)d_in[4];
    const float* enc_attn_b = (const float*)d_in[5];
    const float* enc_ffn_w1 = (const float*)d_in[6];
    const float* enc_ffn_b1 = (const float*)d_in[7];
    const float* enc_ffn_w2 = (const float*)d_in[8];
    const float* enc_ffn_b2 = (const float*)d_in[9];
    const float* enc_ln     = (const float*)d_in[10];
    const float* enc_fln    = (const float*)d_in[11];
    const float* dec_attn_w = (const float*)d_in[12];
    const float* dec_attn_b = (const float*)d_in[13];
    const float* dec_ffn_w1 = (const float*)d_in[14];
    const float* dec_ffn_b1 = (const float*)d_in[15];
    const float* dec_ffn_w2 = (const float*)d_in[16];
    const float* dec_ffn_b2 = (const float*)d_in[17];
    const float* dec_ln     = (const float*)d_in[18];
    const float* dec_fln    = (const float*)d_in[19];
    float* out = (float*)d_out;

    float* ws  = (float*)d_ws;
    const size_t TOKD = (size_t)NTOK * D;   // 524288
    const size_t DD   = (size_t)D * D;
    float* x   = ws;
    float* h   = x   + TOKD;
    float* q   = h   + TOKD;        // qkv contiguous: q, k, v
    float* k   = q   + TOKD;
    float* v   = k   + TOKD;
    float* mem = v   + TOKD;
    float* mid = mem + TOKD;        // NTOK*FF
    float* red = mid + (size_t)NTOK * FF;
    float* ao  = h;                 // alias: h dead once q/k/v computed

    dim3 blk256(256), blk64(64);
    dim3 gQKV(D / 64, NTOK / 64, 3);   // fused q,k,v projections
    dim3 gKV (D / 64, NTOK / 64, 2);   // fused cross k,v projections
    dim3 gP  (D / 64, NTOK / 64, 1);   // single D->D GEMM
    dim3 gF1 (FF / 64, NTOK / 64, 1);  // D->FF
    dim3 gAttn(4, H, B);
    dim3 gGen(V / 64, NTOK / 64);      // 500 x 16

    // ================= encoder =================
    embed_kernel<<<NTOK, blk256, 0, stream>>>(src, tok_emb, pos_emb, x);
    for (int i = 0; i < NL; ++i) {
        const float* w  = enc_attn_w + (size_t)i * 4 * DD;
        const float* bb = enc_attn_b + (size_t)i * 4 * D;
        const float* ln0 = enc_ln + (size_t)((i * 2 + 0) * 2) * D;
        const float* ln1 = enc_ln + (size_t)((i * 2 + 1) * 2) * D;

        ln_kernel<<<NTOK, blk64, 0, stream>>>(x, ln0, ln0 + D, h);
        mgemm<<<gQKV, blk256, 0, stream>>>(h, w, bb, nullptr, q, NTOK, D, D, 0, DD, D, TOKD);
        attn_kernel<<<gAttn, blk256, 0, stream>>>(q, k, v, ao, src, 0);
        mgemm<<<gP, blk256, 0, stream>>>(ao, w + 3 * DD, bb + 3 * D, x, x, NTOK, D, D, 0, 0, 0, 0);

        ln_kernel<<<NTOK, blk64, 0, stream>>>(x, ln1, ln1 + D, h);
        mgemm<<<gF1, blk256, 0, stream>>>(h, enc_ffn_w1 + (size_t)i * D * FF, enc_ffn_b1 + (size_t)i * FF,
                                          nullptr, mid, NTOK, D, FF, 1, 0, 0, 0);
        mgemm<<<gP, blk256, 0, stream>>>(mid, enc_ffn_w2 + (size_t)i * FF * D, enc_ffn_b2 + (size_t)i * D,
                                         x, x, NTOK, FF, D, 0, 0, 0, 0);
    }
    ln_kernel<<<NTOK, blk64, 0, stream>>>(x, enc_fln, enc_fln + D, mem);

    // ================= decoder =================
    embed_kernel<<<NTOK, blk256, 0, stream>>>(tgt, tok_emb, pos_emb, x);
    for (int i = 0; i < NL; ++i) {
        const float* w  = dec_attn_w + (size_t)i * 8 * DD;
        const float* bb = dec_attn_b + (size_t)i * 8 * D;
        const float* ln0 = dec_ln + (size_t)((i * 3 + 0) * 2) * D;
        const float* ln1 = dec_ln + (size_t)((i * 3 + 1) * 2) * D;
        const float* ln2 = dec_ln + (size_t)((i * 3 + 2) * 2) * D;

        // self-attention (causal)
        ln_kernel<<<NTOK, blk64, 0, stream>>>(x, ln0, ln0 + D, h);
        mgemm<<<gQKV, blk256, 0, stream>>>(h, w, bb, nullptr, q, NTOK, D, D, 0, DD, D, TOKD);
        attn_kernel<<<gAttn, blk256, 0, stream>>>(q, k, v, ao, tgt, 1);
        mgemm<<<gP, blk256, 0, stream>>>(ao, w + 3 * DD, bb + 3 * D, x, x, NTOK, D, D, 0, 0, 0, 0);

        // cross-attention
        ln_kernel<<<NTOK, blk64, 0, stream>>>(x, ln1, ln1 + D, h);
        mgemm<<<gP, blk256, 0, stream>>>(h, w + 4 * DD, bb + 4 * D, nullptr, q, NTOK, D, D, 0, 0, 0, 0);
        mgemm<<<gKV, blk256, 0, stream>>>(mem, w + 5 * DD, bb + 5 * D, nullptr, k, NTOK, D, D, 0, DD, D, TOKD);
        attn_kernel<<<gAttn, blk256, 0, stream>>>(q, k, v, ao, src, 0);
        mgemm<<<gP, blk256, 0, stream>>>(ao, w + 7 * DD, bb + 7 * D, x, x, NTOK, D, D, 0, 0, 0, 0);

        // FFN
        ln_kernel<<<NTOK, blk64, 0, stream>>>(x, ln2, ln2 + D, h);
        mgemm<<<gF1, blk256, 0, stream>>>(h, dec_ffn_w1 + (size_t)i * D * FF, dec_ffn_b1 + (size_t)i * FF,
                                          nullptr, mid, NTOK, D, FF, 1, 0, 0, 0);
        mgemm<<<gP, blk256, 0, stream>>>(mid, dec_ffn_w2 + (size_t)i * FF * D, dec_ffn_b2 + (size_t)i * D,
                                         x, x, NTOK, FF, D, 0, 0, 0, 0);
    }
    ln_kernel<<<NTOK, blk64, 0, stream>>>(x, dec_fln, dec_fln + D, h);

    // ================= generator =================
    gemm_nt_mfma<<<gGen, blk256, 0, stream>>>(h, tok_emb, out, NTOK, V, D);
    lse_kernel<<<NTOK, blk256, 0, stream>>>(out, red);
    lsub_kernel<<<dim3(V / 256, NTOK), blk256, 0, stream>>>(out, red);
}

// Round 5
// 3177.422 us; speedup vs baseline: 4.8880x; 3.9853x over previous
//
#include <hip/hip_runtime.h>
#include <hip/hip_bf16.h>

typedef unsigned short u16;
typedef unsigned int u32;
typedef __attribute__((ext_vector_type(8))) short bf8_t;  // 8 bf16 = 16B
typedef __attribute__((ext_vector_type(4))) float f4_t;

#define D 512
#define H 8
#define DK 64
#define NL 6
#define V 32000
#define FF 2048
#define B 8
#define S 128
#define NTOK (B * S)   // 1024

static __device__ inline u16 f2bs(float x) {
    __hip_bfloat16 h = __float2bfloat16(x);
    return *reinterpret_cast<u16*>(&h);
}
static __device__ inline float bs2f(u16 s) {
    return __uint_as_float((u32)s << 16);
}
static __device__ inline float blo(u32 u) { return __uint_as_float(u << 16); }
static __device__ inline float bhi(u32 u) { return __uint_as_float(u & 0xffff0000u); }

// ---------------------------------------------------------------------------
// Weight convert+transpose: in fp32 [R,C] -> out bf16 [C,R]   (z = matrix idx)
// ---------------------------------------------------------------------------
__global__ __launch_bounds__(256) void wconv_t(const float* __restrict__ in,
                                               u16* __restrict__ out,
                                               int R, int C)
{
    __shared__ u16 T[32][40];
    const float* inz = in + (size_t)blockIdx.z * R * C;
    u16* outz = out + (size_t)blockIdx.z * R * C;
    int r0 = blockIdx.y * 32, c0 = blockIdx.x * 32;
    int tid = threadIdx.x;
    {
        int r = tid >> 3, c4 = (tid & 7) * 4;
        float4 f = *(const float4*)&inz[(size_t)(r0 + r) * C + c0 + c4];
        T[c4 + 0][r] = f2bs(f.x);
        T[c4 + 1][r] = f2bs(f.y);
        T[c4 + 2][r] = f2bs(f.z);
        T[c4 + 3][r] = f2bs(f.w);
    }
    __syncthreads();
    {
        int c = tid >> 3, r4 = (tid & 7) * 4;
        u32 lo = ((u32)T[c][r4 + 1] << 16) | T[c][r4 + 0];
        u32 hi = ((u32)T[c][r4 + 3] << 16) | T[c][r4 + 2];
        uint2 p; p.x = lo; p.y = hi;
        *(uint2*)&outz[(size_t)(c0 + c) * R + r0 + r4] = p;
    }
}

// ---------------------------------------------------------------------------
// Elementwise fp32 -> bf16 (tok_emb), 4 elts/thread
// ---------------------------------------------------------------------------
__global__ __launch_bounds__(256) void ec_kernel(const float* __restrict__ in,
                                                 u16* __restrict__ out)
{
    size_t i = ((size_t)blockIdx.x * 256 + threadIdx.x) * 4;
    float4 f = *(const float4*)&in[i];
    uint2 p;
    p.x = ((u32)f2bs(f.y) << 16) | f2bs(f.x);
    p.y = ((u32)f2bs(f.w) << 16) | f2bs(f.z);
    *(uint2*)&out[i] = p;
}

// ---------------------------------------------------------------------------
// Embedding (fp32 residual stream)
// ---------------------------------------------------------------------------
__global__ void embed_kernel(const int* __restrict__ ids,
                             const float* __restrict__ tok,
                             const float* __restrict__ pos,
                             float* __restrict__ X)
{
    int row = blockIdx.x;
    int s   = row & (S - 1);
    int id  = ids[row];
    for (int d = threadIdx.x; d < D; d += 256) {
        X[row * D + d] = tok[(size_t)id * D + d] + pos[s * D + d];
    }
}

// ---------------------------------------------------------------------------
// LayerNorm: fp32 in, bf16 out. One wave per row.
// ---------------------------------------------------------------------------
__global__ void ln_kernel(const float* __restrict__ X,
                          const float* __restrict__ g,
                          const float* __restrict__ bta,
                          u16* __restrict__ Y)
{
    int row  = blockIdx.x;
    int lane = threadIdx.x;          // 64
    float v[8];
    float sum = 0.f;
#pragma unroll
    for (int i = 0; i < 8; ++i) {
        v[i] = X[row * D + i * 64 + lane];
        sum += v[i];
    }
#pragma unroll
    for (int off = 32; off > 0; off >>= 1) sum += __shfl_xor(sum, off);
    float mu = sum * (1.f / D);
    float var = 0.f;
#pragma unroll
    for (int i = 0; i < 8; ++i) { float d = v[i] - mu; var += d * d; }
#pragma unroll
    for (int off = 32; off > 0; off >>= 1) var += __shfl_xor(var, off);
    var *= (1.f / D);
    float r = rsqrtf(var + 1e-6f);
#pragma unroll
    for (int i = 0; i < 8; ++i) {
        int d = i * 64 + lane;
        Y[row * D + d] = f2bs((v[i] - mu) * r * g[d] + bta[d]);
    }
}

// ---------------------------------------------------------------------------
// MFMA GEMM, NT: C = A[1024,K] @ Bt[z][N,K]^T + bias  (+resid fp32) (+relu)
//   A, Bt bf16 (u16); out fp32 or bf16.  Tile MT x 64, BK=64.
//   Pure 16B staging (bf16x8 global load -> ds_write_b128); LDS row stride
//   72 shorts = 144B = 36 dwords == 4 mod 32 -> 2-way bank alias (free).
// ---------------------------------------------------------------------------
template<int MT>   // 32 (128 thr) or 64 (256 thr)
__global__ __launch_bounds__(MT * 4) void mgemm(
    const u16* __restrict__ A, const u16* __restrict__ Bt,
    const float* __restrict__ bias, const float* resid, void* Cout,
    int K, int N, int relu, int obf,
    long wzs, long bzs, long ozs)
{
    constexpr int THREADS = MT * 4;
    __shared__ __align__(16) u16 As[MT][72];
    __shared__ __align__(16) u16 Bs[64][72];

    int z = blockIdx.z;
    const u16* Bz = Bt + (size_t)z * wzs;
    const float* bz = bias ? bias + (size_t)z * bzs : nullptr;

    int tid  = threadIdx.x;
    int col0 = blockIdx.x * 64, row0 = blockIdx.y * MT;
    int wv   = tid >> 6, ln = tid & 63;
    int m16  = ln & 15, quad = ln >> 4;

    f4_t acc[4];
#pragma unroll
    for (int j = 0; j < 4; ++j) acc[j] = (f4_t){0.f, 0.f, 0.f, 0.f};

    for (int k0 = 0; k0 < K; k0 += 64) {
#pragma unroll
        for (int i = tid; i < MT * 8; i += THREADS) {
            int m = i >> 3, k8 = (i & 7) * 8;
            *(bf8_t*)&As[m][k8] = *(const bf8_t*)&A[(size_t)(row0 + m) * K + k0 + k8];
        }
#pragma unroll
        for (int i = tid; i < 512; i += THREADS) {
            int n = i >> 3, k8 = (i & 7) * 8;
            *(bf8_t*)&Bs[n][k8] = *(const bf8_t*)&Bz[(size_t)(col0 + n) * K + k0 + k8];
        }
        __syncthreads();

        bf8_t a0 = *(const bf8_t*)&As[wv * 16 + m16][quad * 8];
        bf8_t a1 = *(const bf8_t*)&As[wv * 16 + m16][32 + quad * 8];
#pragma unroll
        for (int j = 0; j < 4; ++j) {
            bf8_t b0 = *(const bf8_t*)&Bs[j * 16 + m16][quad * 8];
            bf8_t b1 = *(const bf8_t*)&Bs[j * 16 + m16][32 + quad * 8];
            acc[j] = __builtin_amdgcn_mfma_f32_16x16x32_bf16(a0, b0, acc[j], 0, 0, 0);
            acc[j] = __builtin_amdgcn_mfma_f32_16x16x32_bf16(a1, b1, acc[j], 0, 0, 0);
        }
        __syncthreads();
    }

#pragma unroll
    for (int j = 0; j < 4; ++j) {
        int col = col0 + j * 16 + m16;
        float bv = bz ? bz[col] : 0.f;
#pragma unroll
        for (int r = 0; r < 4; ++r) {
            int row = row0 + wv * 16 + quad * 4 + r;
            float val = acc[j][r] + bv;
            if (resid) val += resid[(size_t)row * N + col];
            if (relu) val = fmaxf(val, 0.f);
            if (obf) ((u16*)Cout + (size_t)z * ozs)[(size_t)row * N + col] = f2bs(val);
            else     ((float*)Cout + (size_t)z * ozs)[(size_t)row * N + col] = val;
        }
    }
}

// ---------------------------------------------------------------------------
// Attention, bf16 I/O. Block = (qc,h,b), 256 thr = 4 waves, wave owns 8 q-rows.
// K,V,Q staged once (1 barrier); per-q work is barrier-free:
//   score: lane<->keys {lane, lane+64}, packed-bf16 dot over d;
//   softmax: 64-lane shuffle butterflies;
//   PV: lane = (d-pair, t-half), Vp packed uint; combine via shfl_xor(32).
// ---------------------------------------------------------------------------
__global__ __launch_bounds__(256) void attn_kernel(
    const u16* __restrict__ Qb, const u16* __restrict__ Kb,
    const u16* __restrict__ Vb, u16* __restrict__ Ob,
    const int* __restrict__ mask_ids, int causal)
{
    __shared__ u16 Ks[128][66];     // [t][d], 132B rows: u32 reads 2-way free
    __shared__ u32 Vp[128][36];     // [t][d/2] packed bf16-pairs
    __shared__ u16 Qs[32][66];
    __shared__ float es[4][132];

    int qc = blockIdx.x;   // 0..3
    int h  = blockIdx.y;
    int b  = blockIdx.z;
    int tid = threadIdx.x;

    // stage K and V (128 tokens x 64 dims)
    for (int i = tid; i < 1024; i += 256) {
        int t = i >> 3, d8 = (i & 7) * 8;
        size_t src = (size_t)(b * S + t) * D + h * DK + d8;
        uint4 kv = *(const uint4*)&Kb[src];
        *(u32*)&Ks[t][d8 + 0] = kv.x;
        *(u32*)&Ks[t][d8 + 2] = kv.y;
        *(u32*)&Ks[t][d8 + 4] = kv.z;
        *(u32*)&Ks[t][d8 + 6] = kv.w;
        uint4 vv = *(const uint4*)&Vb[src];
        *(uint4*)&Vp[t][d8 >> 1] = vv;
    }
    // stage Q (32 rows of this block)
    {
        int m = tid >> 3, d8 = (tid & 7) * 8;
        uint4 qv = *(const uint4*)&Qb[(size_t)(b * S + qc * 32 + m) * D + h * DK + d8];
        *(u32*)&Qs[m][d8 + 0] = qv.x;
        *(u32*)&Qs[m][d8 + 2] = qv.y;
        *(u32*)&Qs[m][d8 + 4] = qv.z;
        *(u32*)&Qs[m][d8 + 6] = qv.w;
    }
    __syncthreads();

    int w      = tid >> 6;        // wave 0..3
    int lane   = tid & 63;
    int d2     = lane & 31;
    int th     = lane >> 5;       // t-half for PV
    bool pad0  = (mask_ids[b * S + lane] == 1);
    bool pad1  = (mask_ids[b * S + 64 + lane] == 1);

    for (int qi = 0; qi < 8; ++qi) {
        int qloc = w * 8 + qi;
        int qpos = qc * 32 + qloc;

        // ---- scores for keys t=lane and t=lane+64 ----
        float s0 = 0.f, s1 = 0.f;
#pragma unroll
        for (int i = 0; i < 32; ++i) {
            u32 qu = *(const u32*)&Qs[qloc][2 * i];
            u32 k0 = *(const u32*)&Ks[lane][2 * i];
            u32 k1 = *(const u32*)&Ks[lane + 64][2 * i];
            float ql = blo(qu), qh = bhi(qu);
            s0 += ql * blo(k0) + qh * bhi(k0);
            s1 += ql * blo(k1) + qh * bhi(k1);
        }
        s0 *= 0.125f; s1 *= 0.125f;
        if (pad0 || (causal && lane > qpos))        s0 = -1e30f;
        if (pad1 || (causal && (lane + 64) > qpos)) s1 = -1e30f;

        // ---- softmax (64-lane butterflies) ----
        float mx = fmaxf(s0, s1);
#pragma unroll
        for (int off = 32; off > 0; off >>= 1) mx = fmaxf(mx, __shfl_xor(mx, off));
        float e0 = __expf(s0 - mx), e1 = __expf(s1 - mx);
        float l = e0 + e1;
#pragma unroll
        for (int off = 32; off > 0; off >>= 1) l += __shfl_xor(l, off);
        float inv = 1.f / l;
        es[w][lane]      = e0 * inv;
        es[w][lane + 64] = e1 * inv;

        // ---- PV: lane = (d2, th); partial over its 64 t's ----
        float o0 = 0.f, o1 = 0.f;
#pragma unroll 8
        for (int i = 0; i < 64; ++i) {
            int t = th * 64 + i;
            float e = es[w][t];
            u32 vu = Vp[t][d2];
            o0 += e * blo(vu);
            o1 += e * bhi(vu);
        }
        o0 += __shfl_xor(o0, 32);
        o1 += __shfl_xor(o1, 32);
        if (th == 0) {
            u32 packed = ((u32)f2bs(o1) << 16) | f2bs(o0);
            *(u32*)&Ob[(size_t)(b * S + qpos) * D + h * DK + 2 * d2] = packed;
        }
    }
}

// ---------------------------------------------------------------------------
// log-softmax pieces (fp32, unchanged)
// ---------------------------------------------------------------------------
__global__ void lse_kernel(const float* __restrict__ logits,
                           float* __restrict__ c)
{
    __shared__ float ms[256], ls[256];
    int row = blockIdx.x;
    int tid = threadIdx.x;
    float m = -1e30f, l = 0.f;
    for (int j = tid; j < V; j += 256) {
        float x = logits[(size_t)row * V + j];
        if (x > m) { l = l * __expf(m - x) + 1.f; m = x; }
        else       { l += __expf(x - m); }
    }
    ms[tid] = m; ls[tid] = l;
    __syncthreads();
    for (int s2 = 128; s2 > 0; s2 >>= 1) {
        if (tid < s2) {
            float m1 = ms[tid], l1 = ls[tid];
            float m2 = ms[tid + s2], l2 = ls[tid + s2];
            float M = fmaxf(m1, m2);
            ls[tid] = l1 * __expf(m1 - M) + l2 * __expf(m2 - M);
            ms[tid] = M;
        }
        __syncthreads();
    }
    if (tid == 0) c[row] = ms[0] + logf(ls[0]);
}

__global__ void lsub_kernel(float* __restrict__ out, const float* __restrict__ c)
{
    int row = blockIdx.y;
    int j = blockIdx.x * 256 + threadIdx.x;
    size_t idx = (size_t)row * V + j;
    out[idx] = out[idx] - c[row];
}

// ---------------------------------------------------------------------------
// Host orchestration
// ---------------------------------------------------------------------------
extern "C" void kernel_launch(void* const* d_in, const int* in_sizes, int n_in,
                              void* d_out, int out_size, void* d_ws, size_t ws_size,
                              hipStream_t stream)
{
    const int*   src        = (const int*)d_in[0];
    const int*   tgt        = (const int*)d_in[1];
    const float* tok_emb    = (const float*)d_in[2];
    const float* pos_emb    = (const float*)d_in[3];
    const float* enc_attn_w = (const float*)d_in[4];
    const float* enc_attn_b = (const float*)d_in[5];
    const float* enc_ffn_w1 = (const float*)d_in[6];
    const float* enc_ffn_b1 = (const float*)d_in[7];
    const float* enc_ffn_w2 = (const float*)d_in[8];
    const float* enc_ffn_b2 = (const float*)d_in[9];
    const float* enc_ln     = (const float*)d_in[10];
    const float* enc_fln    = (const float*)d_in[11];
    const float* dec_attn_w = (const float*)d_in[12];
    const float* dec_attn_b = (const float*)d_in[13];
    const float* dec_ffn_w1 = (const float*)d_in[14];
    const float* dec_ffn_b1 = (const float*)d_in[15];
    const float* dec_ffn_w2 = (const float*)d_in[16];
    const float* dec_ffn_b2 = (const float*)d_in[17];
    const float* dec_ln     = (const float*)d_in[18];
    const float* dec_fln    = (const float*)d_in[19];
    float* out = (float*)d_out;

    const size_t TOKD = (size_t)NTOK * D;
    const size_t DD   = (size_t)D * D;
    const size_t DF   = (size_t)D * FF;

    char* p = (char*)d_ws;
    auto carve = [&](size_t bytes) {
        void* r = (void*)p;
        p += (bytes + 255) & ~(size_t)255;
        return r;
    };
    u16* wtEA  = (u16*)carve(24 * DD * 2);
    u16* wtEF1 = (u16*)carve(6 * DF * 2);
    u16* wtEF2 = (u16*)carve(6 * DF * 2);
    u16* wtDA  = (u16*)carve(48 * DD * 2);
    u16* wtDF1 = (u16*)carve(6 * DF * 2);
    u16* wtDF2 = (u16*)carve(6 * DF * 2);
    u16* emb16 = (u16*)carve((size_t)V * D * 2);
    float* x   = (float*)carve(TOKD * 4);
    u16* h16   = (u16*)carve(TOKD * 2);
    u16* q16   = (u16*)carve(TOKD * 2 * 3);
    u16* k16   = q16 + TOKD;
    u16* v16   = k16 + TOKD;
    u16* ao16  = (u16*)carve(TOKD * 2);
    u16* mem16 = (u16*)carve(TOKD * 2);
    u16* mid16 = (u16*)carve((size_t)NTOK * FF * 2);
    float* red = (float*)carve(NTOK * 4);

    dim3 b256(256), b128(128), b64(64);
    dim3 gQKV(8, 32, 3);
    dim3 gKV (8, 32, 2);
    dim3 gP  (8, 32, 1);
    dim3 gF1 (32, 16, 1);     // MT=64, N=2048
    dim3 gF2 (8, 32, 1);      // MT=32, K=2048
    dim3 gGen(500, 16, 1);    // MT=64, N=32000
    dim3 gAttn(4, H, B);

    // ---- preprocessing: weights -> bf16 [N,K] ----
    wconv_t<<<dim3(16, 16, 24), b256, 0, stream>>>(enc_attn_w, wtEA, 512, 512);
    wconv_t<<<dim3(64, 16, 6),  b256, 0, stream>>>(enc_ffn_w1, wtEF1, 512, 2048);
    wconv_t<<<dim3(16, 64, 6),  b256, 0, stream>>>(enc_ffn_w2, wtEF2, 2048, 512);
    wconv_t<<<dim3(16, 16, 48), b256, 0, stream>>>(dec_attn_w, wtDA, 512, 512);
    wconv_t<<<dim3(64, 16, 6),  b256, 0, stream>>>(dec_ffn_w1, wtDF1, 512, 2048);
    wconv_t<<<dim3(16, 64, 6),  b256, 0, stream>>>(dec_ffn_w2, wtDF2, 2048, 512);
    ec_kernel<<<16000, b256, 0, stream>>>(tok_emb, emb16);

    // ================= encoder =================
    embed_kernel<<<NTOK, b256, 0, stream>>>(src, tok_emb, pos_emb, x);
    for (int i = 0; i < NL; ++i) {
        const float* bb  = enc_attn_b + (size_t)i * 4 * D;
        const float* ln0 = enc_ln + (size_t)((i * 2 + 0) * 2) * D;
        const float* ln1 = enc_ln + (size_t)((i * 2 + 1) * 2) * D;

        ln_kernel<<<NTOK, b64, 0, stream>>>(x, ln0, ln0 + D, h16);
        mgemm<32><<<gQKV, b128, 0, stream>>>(h16, wtEA + i * 4 * DD, bb, nullptr, q16,
                                             512, 512, 0, 1, DD, D, TOKD);
        attn_kernel<<<gAttn, b256, 0, stream>>>(q16, k16, v16, ao16, src, 0);
        mgemm<32><<<gP, b128, 0, stream>>>(ao16, wtEA + (i * 4 + 3) * DD, bb + 3 * D, x, x,
                                           512, 512, 0, 0, 0, 0, 0);

        ln_kernel<<<NTOK, b64, 0, stream>>>(x, ln1, ln1 + D, h16);
        mgemm<64><<<gF1, b256, 0, stream>>>(h16, wtEF1 + i * DF, enc_ffn_b1 + (size_t)i * FF,
                                            nullptr, mid16, 512, 2048, 1, 1, 0, 0, 0);
        mgemm<32><<<gF2, b128, 0, stream>>>(mid16, wtEF2 + i * DF, enc_ffn_b2 + (size_t)i * D,
                                            x, x, 2048, 512, 0, 0, 0, 0, 0);
    }
    ln_kernel<<<NTOK, b64, 0, stream>>>(x, enc_fln, enc_fln + D, mem16);

    // ================= decoder =================
    embed_kernel<<<NTOK, b256, 0, stream>>>(tgt, tok_emb, pos_emb, x);
    for (int i = 0; i < NL; ++i) {
        const float* bb  = dec_attn_b + (size_t)i * 8 * D;
        const u16*   wt  = wtDA + (size_t)i * 8 * DD;
        const float* ln0 = dec_ln + (size_t)((i * 3 + 0) * 2) * D;
        const float* ln1 = dec_ln + (size_t)((i * 3 + 1) * 2) * D;
        const float* ln2 = dec_ln + (size_t)((i * 3 + 2) * 2) * D;

        // self-attention (causal)
        ln_kernel<<<NTOK, b64, 0, stream>>>(x, ln0, ln0 + D, h16);
        mgemm<32><<<gQKV, b128, 0, stream>>>(h16, wt, bb, nullptr, q16,
                                             512, 512, 0, 1, DD, D, TOKD);
        attn_kernel<<<gAttn, b256, 0, stream>>>(q16, k16, v16, ao16, tgt, 1);
        mgemm<32><<<gP, b128, 0, stream>>>(ao16, wt + 3 * DD, bb + 3 * D, x, x,
                                           512, 512, 0, 0, 0, 0, 0);

        // cross-attention
        ln_kernel<<<NTOK, b64, 0, stream>>>(x, ln1, ln1 + D, h16);
        mgemm<32><<<gP, b128, 0, stream>>>(h16, wt + 4 * DD, bb + 4 * D, nullptr, q16,
                                           512, 512, 0, 1, 0, 0, 0);
        mgemm<32><<<gKV, b128, 0, stream>>>(mem16, wt + 5 * DD, bb + 5 * D, nullptr, k16,
                                            512, 512, 0, 1, DD, D, TOKD);
        attn_kernel<<<gAttn, b256, 0, stream>>>(q16, k16, v16, ao16, src, 0);
        mgemm<32><<<gP, b128, 0, stream>>>(ao16, wt + 7 * DD, bb + 7 * D, x, x,
                                           512, 512, 0, 0, 0, 0, 0);

        // FFN
        ln_kernel<<<NTOK, b64, 0, stream>>>(x, ln2, ln2 + D, h16);
        mgemm<64><<<gF1, b256, 0, stream>>>(h16, wtDF1 + i * DF, dec_ffn_b1 + (size_t)i * FF,
                                            nullptr, mid16, 512, 2048, 1, 1, 0, 0, 0);
        mgemm<32><<<gF2, b128, 0, stream>>>(mid16, wtDF2 + i * DF, dec_ffn_b2 + (size_t)i * D,
                                            x, x, 2048, 512, 0, 0, 0, 0, 0);
    }
    ln_kernel<<<NTOK, b64, 0, stream>>>(x, dec_fln, dec_fln + D, h16);

    // ================= generator =================
    mgemm<64><<<gGen, b256, 0, stream>>>(h16, emb16, nullptr, nullptr, out,
                                         512, V, 0, 0, 0, 0, 0);
    lse_kernel<<<NTOK, b256, 0, stream>>>(out, red);
    lsub_kernel<<<dim3(V / 256, NTOK), b256, 0, stream>>>(out, red);
}